// Round 11
// baseline (43.057 us; speedup 1.0000x reference)
//
#include <hip/hip_runtime.h>
#include <math.h>

// Problem constants
#define NB 8
#define NN 128
static constexpr float NEGV = -1000000.0f;

// One workgroup per (b, r-PAIR). 1024 threads = 16 waves. Wave w owns
// s = w + 16*si (si=0..7) and loads BOTH r and r+1 for each s back-to-back:
// two 1KiB wave-loads at consecutive addresses -> 2KiB-sequential DRAM
// stream (granularity theory: 1KiB=4.3TB/s, model predicts 2KiB~5.3TB/s).
// 16 named float4 regs/thread (64 VGPR data; ~111 total <= 128 cap of
// 1024-thread blocks). Full s-range in block -> single-kernel softmax.
// lane l: e = l>>5, c4 = l&31.
__global__ __launch_bounds__(1024)
void edge_attn_kernel(const float* __restrict__ edge_msgs,
                      const float* __restrict__ node_states,
                      const float* __restrict__ W,
                      const float* __restrict__ bvec,
                      const int*   __restrict__ edges,
                      float* __restrict__ out) {
    const int blk = blockIdx.x;
    const int rp  = blk & 63;
    const int b   = blk >> 6;
    const int r0  = rp * 2;

    const int t  = threadIdx.x;
    const int w  = t >> 6;      // wave 0..15
    const int l  = t & 63;
    const int e  = l >> 5;      // 0/1
    const int c4 = l & 31;

    // part: quad-partial scores for ONE r at a time: [s*68 + e*32 + h*8 + g]
    // (34.8KB). After both softmax phases it is dead; outbuf aliases it.
    __shared__ float part[128 * 68];
    __shared__ float wts [2][2 * 128 * 5];   // [rr][e*640 + s*5 + h]
    __shared__ float ebias[2][128 * 2];      // [rr][s*2 + e]
    __shared__ float nodep[2][4];            // [rr][h]
    float (*outbuf)[4][128] = (float (*)[4][128])part;  // [wave][h][c], 32KB

    // ---- W_msg fragment for this lane's c-chunk
    float4 wm0 = *(const float4*)(W +   0 + c4 * 4);
    float4 wm1 = *(const float4*)(W + 256 + c4 * 4);
    float4 wm2 = *(const float4*)(W + 512 + c4 * 4);
    float4 wm3 = *(const float4*)(W + 768 + c4 * 4);

    // ---- stream base: (b, r0). per-s stride = 32768 floats; r1 = +256.
    const float* bp = edge_msgs
        + (size_t)b * (NN * NN * 256)
        + (size_t)r0 * 256
        + e * 128 + c4 * 4;

    float4 P0, P1, P2, P3, P4, P5, P6, P7;   // r0 data, s = w + 16*si
    float4 Q0, Q1, Q2, Q3, Q4, Q5, Q6, Q7;   // r1 data

    // issue pairs back-to-back: addresses of the pair are 1KiB apart
#define LOADP(i)                                                               \
    P##i = *(const float4*)(bp + (size_t)(w + 16 * (i)) * 32768);              \
    Q##i = *(const float4*)(bp + (size_t)(w + 16 * (i)) * 32768 + 256);
    LOADP(0) LOADP(1) LOADP(2) LOADP(3)
    LOADP(4) LOADP(5) LOADP(6) LOADP(7)
#undef LOADP

    // ---- node projections for r0 (wave 0) and r1 (wave 1)
    if (w < 2) {
        int rr = w;
        float2 nv  = *(const float2*)(node_states + ((size_t)b * NN + r0 + rr) * 128 + l * 2);
        float2 wn0 = *(const float2*)(W + 128 + l * 2);
        float2 wn1 = *(const float2*)(W + 384 + l * 2);
        float2 wn2 = *(const float2*)(W + 640 + l * 2);
        float2 wn3 = *(const float2*)(W + 896 + l * 2);
        float np0 = nv.x * wn0.x + nv.y * wn0.y;
        float np1 = nv.x * wn1.x + nv.y * wn1.y;
        float np2 = nv.x * wn2.x + nv.y * wn2.y;
        float np3 = nv.x * wn3.x + nv.y * wn3.y;
        #pragma unroll
        for (int m = 32; m >= 1; m >>= 1) {
            np0 += __shfl_xor(np0, m);
            np1 += __shfl_xor(np1, m);
            np2 += __shfl_xor(np2, m);
            np3 += __shfl_xor(np3, m);
        }
        if (l == 0) { nodep[rr][0] = np0; nodep[rr][1] = np1; nodep[rr][2] = np2; nodep[rr][3] = np3; }
    }

    // ---- edge mask bias, both r: 512 threads load one int each
    if (t < 512) {
        int s  = t >> 2;
        int rr = (t >> 1) & 1;
        int ec = t & 1;
        int ev = edges[(((size_t)b * NN + s) * NN + (r0 + rr)) * 3 + 1 + ec];
        ebias[rr][s * 2 + ec] = (1.0f - (float)ev) * NEGV;
    }

    const int hsel = l & 3;
    const int g    = (l >> 2) & 7;
    const bool o1  = (l & 1) != 0;
    const bool o2  = (l & 2) != 0;

#define SCOREV(d, si) {                                                        \
    float p0 = d.x * wm0.x + d.y * wm0.y + d.z * wm0.z + d.w * wm0.w;          \
    float p1 = d.x * wm1.x + d.y * wm1.y + d.z * wm1.z + d.w * wm1.w;          \
    float p2 = d.x * wm2.x + d.y * wm2.y + d.z * wm2.z + d.w * wm2.w;          \
    float p3 = d.x * wm3.x + d.y * wm3.y + d.z * wm3.z + d.w * wm3.w;          \
    float x01 = o1 ? p1 : p0, y01 = o1 ? p0 : p1;                              \
    float x23 = o1 ? p3 : p2, y23 = o1 ? p2 : p3;                              \
    float r01 = x01 + __shfl_xor(y01, 1);                                      \
    float r23 = x23 + __shfl_xor(y23, 1);                                      \
    float x2 = o2 ? r23 : r01, y2 = o2 ? r01 : r23;                            \
    float val = x2 + __shfl_xor(y2, 2);                                        \
    part[(w + 16 * (si)) * 68 + e * 32 + hsel * 8 + g] = val;                  \
}

// softmax over all 128 s for one r (t<256: 8 groups (es,h) x 32 lanes)
#define SMAX(rr) if (t < 256) {                                                \
    int p  = t >> 5;                                                           \
    int j  = t & 31;                                                           \
    int es = p & 1;                                                            \
    int h  = p >> 1;                                                           \
    float bb = bvec[h] + nodep[rr][h];                                         \
    float y0, y1, y2, y3;                                                      \
    {                                                                          \
        float x; const float* q;                                               \
        q = &part[(j +  0) * 68 + es * 32 + h * 8];                            \
        { float4 qa = *(const float4*)q, qb = *(const float4*)(q + 4);         \
          x = qa.x+qa.y+qa.z+qa.w + qb.x+qb.y+qb.z+qb.w + bb;                  \
          x = x > 0.f ? x : expm1f(x); y0 = x + ebias[rr][(j+ 0)*2+es]; }      \
        q = &part[(j + 32) * 68 + es * 32 + h * 8];                            \
        { float4 qa = *(const float4*)q, qb = *(const float4*)(q + 4);         \
          x = qa.x+qa.y+qa.z+qa.w + qb.x+qb.y+qb.z+qb.w + bb;                  \
          x = x > 0.f ? x : expm1f(x); y1 = x + ebias[rr][(j+32)*2+es]; }      \
        q = &part[(j + 64) * 68 + es * 32 + h * 8];                            \
        { float4 qa = *(const float4*)q, qb = *(const float4*)(q + 4);         \
          x = qa.x+qa.y+qa.z+qa.w + qb.x+qb.y+qb.z+qb.w + bb;                  \
          x = x > 0.f ? x : expm1f(x); y2 = x + ebias[rr][(j+64)*2+es]; }      \
        q = &part[(j + 96) * 68 + es * 32 + h * 8];                            \
        { float4 qa = *(const float4*)q, qb = *(const float4*)(q + 4);         \
          x = qa.x+qa.y+qa.z+qa.w + qb.x+qb.y+qb.z+qb.w + bb;                  \
          x = x > 0.f ? x : expm1f(x); y3 = x + ebias[rr][(j+96)*2+es]; }      \
    }                                                                          \
    float m4 = fmaxf(fmaxf(y0, y1), fmaxf(y2, y3));                            \
    _Pragma("unroll")                                                          \
    for (int m = 16; m >= 1; m >>= 1) m4 = fmaxf(m4, __shfl_xor(m4, m));       \
    y0 = __expf(y0 - m4); y1 = __expf(y1 - m4);                                \
    y2 = __expf(y2 - m4); y3 = __expf(y3 - m4);                                \
    float sum = y0 + y1 + y2 + y3;                                             \
    _Pragma("unroll")                                                          \
    for (int m = 16; m >= 1; m >>= 1) sum += __shfl_xor(sum, m);               \
    float inv = 1.0f / sum;                                                    \
    wts[rr][es * 640 + (j +  0) * 5 + h] = y0 * inv;                           \
    wts[rr][es * 640 + (j + 32) * 5 + h] = y1 * inv;                           \
    wts[rr][es * 640 + (j + 64) * 5 + h] = y2 * inv;                           \
    wts[rr][es * 640 + (j + 96) * 5 + h] = y3 * inv;                           \
}

    // ---- scores r0 -> softmax r0 -> scores r1 -> softmax r1
    SCOREV(P0, 0) SCOREV(P1, 1) SCOREV(P2, 2) SCOREV(P3, 3)
    SCOREV(P4, 4) SCOREV(P5, 5) SCOREV(P6, 6) SCOREV(P7, 7)
    __syncthreads();
    SMAX(0)
    __syncthreads();
    SCOREV(Q0, 0) SCOREV(Q1, 1) SCOREV(Q2, 2) SCOREV(Q3, 3)
    SCOREV(Q4, 4) SCOREV(Q5, 5) SCOREV(Q6, 6) SCOREV(Q7, 7)
    __syncthreads();
    SMAX(1)
    __syncthreads();   // part now dead -> outbuf may reuse it
#undef SCOREV
#undef SMAX

#define AGGV(d, si, rr) {                                                      \
    int s = w + 16 * (si);                                                     \
    float w0 = wts[rr][e * 640 + s * 5 + 0];                                   \
    float w1 = wts[rr][e * 640 + s * 5 + 1];                                   \
    float w2 = wts[rr][e * 640 + s * 5 + 2];                                   \
    float w3 = wts[rr][e * 640 + s * 5 + 3];                                   \
    a0.x += w0 * d.x; a0.y += w0 * d.y; a0.z += w0 * d.z; a0.w += w0 * d.w;    \
    a1.x += w1 * d.x; a1.y += w1 * d.y; a1.z += w1 * d.z; a1.w += w1 * d.w;    \
    a2.x += w2 * d.x; a2.y += w2 * d.y; a2.z += w2 * d.z; a2.w += w2 * d.w;    \
    a3.x += w3 * d.x; a3.y += w3 * d.y; a3.z += w3 * d.z; a3.w += w3 * d.w;    \
}

#define AGGPHASE(PFX, rr)                                                      \
    {                                                                          \
        float4 a0 = {0,0,0,0}, a1 = {0,0,0,0}, a2 = {0,0,0,0}, a3 = {0,0,0,0}; \
        AGGV(PFX##0, 0, rr) AGGV(PFX##1, 1, rr)                                \
        AGGV(PFX##2, 2, rr) AGGV(PFX##3, 3, rr)                                \
        AGGV(PFX##4, 4, rr) AGGV(PFX##5, 5, rr)                                \
        AGGV(PFX##6, 6, rr) AGGV(PFX##7, 7, rr)                                \
        a0.x += __shfl_xor(a0.x, 32); a0.y += __shfl_xor(a0.y, 32);            \
        a0.z += __shfl_xor(a0.z, 32); a0.w += __shfl_xor(a0.w, 32);            \
        a1.x += __shfl_xor(a1.x, 32); a1.y += __shfl_xor(a1.y, 32);            \
        a1.z += __shfl_xor(a1.z, 32); a1.w += __shfl_xor(a1.w, 32);            \
        a2.x += __shfl_xor(a2.x, 32); a2.y += __shfl_xor(a2.y, 32);            \
        a2.z += __shfl_xor(a2.z, 32); a2.w += __shfl_xor(a2.w, 32);            \
        a3.x += __shfl_xor(a3.x, 32); a3.y += __shfl_xor(a3.y, 32);            \
        a3.z += __shfl_xor(a3.z, 32); a3.w += __shfl_xor(a3.w, 32);            \
        if (e == 0) {                                                          \
            *(float4*)&outbuf[w][0][c4 * 4] = a0;                              \
            *(float4*)&outbuf[w][1][c4 * 4] = a1;                              \
            *(float4*)&outbuf[w][2][c4 * 4] = a2;                              \
            *(float4*)&outbuf[w][3][c4 * 4] = a3;                              \
        }                                                                      \
    }                                                                          \
    __syncthreads();                                                           \
    if (t < 512) {                                                             \
        int h = t >> 7;                                                        \
        int c = t & 127;                                                       \
        float sv = 0.f;                                                        \
        _Pragma("unroll")                                                      \
        for (int k = 0; k < 16; ++k) sv += outbuf[k][h][c];                    \
        out[((size_t)b * NN + (r0 + rr)) * 512 + t] = sv;                      \
    }                                                                          \
    __syncthreads();

    AGGPHASE(P, 0)
    AGGPHASE(Q, 1)
#undef AGGPHASE
#undef AGGV
}

extern "C" void kernel_launch(void* const* d_in, const int* in_sizes, int n_in,
                              void* d_out, int out_size, void* d_ws, size_t ws_size,
                              hipStream_t stream) {
    const float* edge_msgs   = (const float*)d_in[0];
    const float* node_states = (const float*)d_in[1];
    const float* W           = (const float*)d_in[2];
    const float* bvec        = (const float*)d_in[3];
    const int*   edges       = (const int*)d_in[4];
    float* out = (float*)d_out;

    dim3 grid(NB * (NN / 2));   // 512 blocks: (b, r-pair)
    dim3 block(1024);
    edge_attn_kernel<<<grid, block, 0, stream>>>(edge_msgs, node_states, W, bvec, edges, out);
}